// Round 2
// baseline (317.221 us; speedup 1.0000x reference)
//
#include <hip/hip_runtime.h>

// Fused ResidualTokenAdapter, barrier-free formulation.
// LN folded into down-proj: with dw'[n,k] = gamma_k*dw[n,k], sdw_n = sum_k dw'[n,k],
// db'_n = db_n + sum_k beta_k*dw[n,k]:
//   h_n = rs * ( dot(x_raw, dw'_n) - mu*sdw_n ) + db'_n
// => down-GEMM consumes RAW x; stats only needed as a post-hoc scalar correction.
// Each wave independently owns 16 rows: loads A-fragments straight from global
// (lane(q,c): row c, cols ks*32+q*8 -> 4 q-lanes cover each 128B line exactly once),
// accumulates stats from the same registers, corrects, GELUs, transposes g through
// a 2.3 KB per-wave LDS tile (same-wave ordering only), and streams the up-GEMM +
// residual + store. LDS/block: 9.2 KB. Workspace: exactly 256 KB (proven size);
// the 128 floats of folded stats live in module-scope __device__ memory instead.

#define HDIM 1024
#define BDIM 64
#define GPAD 72   // g-tile row stride (shorts)

using s16x8 = __attribute__((ext_vector_type(8))) short;
using f32x4 = __attribute__((ext_vector_type(4))) float;

__device__ float g_wstat[128];   // [0:64) sdw, [64:128) db2 — static, not workspace

__device__ __forceinline__ short f2bf(float f) {
  unsigned u = __builtin_bit_cast(unsigned, f);
  u += 0x7fffu + ((u >> 16) & 1u);          // round-to-nearest-even
  return (short)(u >> 16);
}
__device__ __forceinline__ float bf2f(short s) {
  unsigned u = ((unsigned)(unsigned short)s) << 16;
  return __builtin_bit_cast(float, u);
}

// prep: blocks 0..63 convert weights to bf16 (gamma folded into dw);
// block 64 computes sdw[64] (bf16-rounded, matching GEMM operand) and db2[64].
extern "C" __global__ void prep_weights(const float* __restrict__ dw,
                                        const float* __restrict__ uw,
                                        const float* __restrict__ nw,
                                        const float* __restrict__ nb,
                                        const float* __restrict__ db,
                                        short* __restrict__ wsbf) {
  const int b = blockIdx.x;
  if (b < 64) {
    int tid = b * 256 + threadIdx.x;                 // 0..16383
    if (tid < 8192) {                                // dw' = gamma * dw
      int off = tid * 8;
      int k = off & (HDIM - 1);
      f32x4 v0 = *(const f32x4*)(dw + off);
      f32x4 v1 = *(const f32x4*)(dw + off + 4);
      f32x4 g0 = *(const f32x4*)(nw + k);
      f32x4 g1 = *(const f32x4*)(nw + k + 4);
      s16x8 o;
#pragma unroll
      for (int j = 0; j < 4; ++j) {
        o[j]     = f2bf(v0[j] * g0[j]);
        o[j + 4] = f2bf(v1[j] * g1[j]);
      }
      *(s16x8*)(wsbf + tid * 8) = o;
    } else {                                         // uw unchanged
      int off = (tid - 8192) * 8;
      f32x4 v0 = *(const f32x4*)(uw + off);
      f32x4 v1 = *(const f32x4*)(uw + off + 4);
      s16x8 o;
#pragma unroll
      for (int j = 0; j < 4; ++j) { o[j] = f2bf(v0[j]); o[j + 4] = f2bf(v1[j]); }
      *(s16x8*)(wsbf + tid * 8) = o;
    }
  } else {
    // stats: 4 threads per n, each sums 256 k's
    const int t = threadIdx.x;
    const int n = t >> 2, p = t & 3;
    const float* dwn = dw + n * HDIM;
    float s1 = 0.f, s2 = 0.f;
    for (int j = 0; j < 32; ++j) {
      int k = p * 256 + j * 8;
      f32x4 v0 = *(const f32x4*)(dwn + k);
      f32x4 v1 = *(const f32x4*)(dwn + k + 4);
      f32x4 g0 = *(const f32x4*)(nw + k);
      f32x4 g1 = *(const f32x4*)(nw + k + 4);
      f32x4 b0 = *(const f32x4*)(nb + k);
      f32x4 b1 = *(const f32x4*)(nb + k + 4);
#pragma unroll
      for (int jj = 0; jj < 4; ++jj) {
        s1 += bf2f(f2bf(v0[jj] * g0[jj])) + bf2f(f2bf(v1[jj] * g1[jj]));
        s2 += v0[jj] * b0[jj] + v1[jj] * b1[jj];
      }
    }
    s1 += __shfl_xor(s1, 1); s1 += __shfl_xor(s1, 2);
    s2 += __shfl_xor(s2, 1); s2 += __shfl_xor(s2, 2);
    if (p == 0) {
      g_wstat[n]      = s1;            // sdw
      g_wstat[64 + n] = db[n] + s2;    // db2
    }
  }
}

extern "C" __global__ __launch_bounds__(256, 2)
void adapter_fused(const float* __restrict__ x,
                   const float* __restrict__ ub,
                   const short* __restrict__ dwb,
                   const short* __restrict__ uwb,
                   float* __restrict__ out)
{
  __shared__ __align__(16) short gbf[4][16][GPAD];   // per-wave g transposer, 9.2 KB

  const int t    = threadIdx.x;
  const int w    = t >> 6;            // wave 0..3 (independent; no block barriers)
  const int lane = t & 63;
  const int q    = lane >> 4;
  const int c    = lane & 15;
  const size_t rowbase = ((size_t)blockIdx.x * 4 + w) * 16;

  // A direct from global in fragment order; B (dw') L2-resident.
  const float* pA  = x   + (rowbase + c) * HDIM + q * 8;
  const short* pB0 = dwb + (size_t)( 0 + c) * HDIM + q * 8;
  const short* pB1 = dwb + (size_t)(16 + c) * HDIM + q * 8;
  const short* pB2 = dwb + (size_t)(32 + c) * HDIM + q * 8;
  const short* pB3 = dwb + (size_t)(48 + c) * HDIM + q * 8;

  f32x4 acc0 = {0.f,0.f,0.f,0.f}, acc1 = acc0, acc2 = acc0, acc3 = acc0;
  float sum = 0.f, ssq = 0.f;

#pragma unroll 4
  for (int ks = 0; ks < 32; ++ks) {
    f32x4 v0 = *(const f32x4*)(pA + ks * 32);        // imm offsets, no addr VALU
    f32x4 v1 = *(const f32x4*)(pA + ks * 32 + 4);
    s16x8 b0 = *(const s16x8*)(pB0 + ks * 32);
    s16x8 b1 = *(const s16x8*)(pB1 + ks * 32);
    s16x8 b2 = *(const s16x8*)(pB2 + ks * 32);
    s16x8 b3 = *(const s16x8*)(pB3 + ks * 32);
    s16x8 a;
#pragma unroll
    for (int j = 0; j < 4; ++j) {
      float f0 = v0[j]; sum += f0; ssq += f0 * f0; a[j]     = f2bf(f0);
      float f1 = v1[j]; sum += f1; ssq += f1 * f1; a[j + 4] = f2bf(f1);
    }
    acc0 = __builtin_amdgcn_mfma_f32_16x16x32_bf16(a, b0, acc0, 0, 0, 0);
    acc1 = __builtin_amdgcn_mfma_f32_16x16x32_bf16(a, b1, acc1, 0, 0, 0);
    acc2 = __builtin_amdgcn_mfma_f32_16x16x32_bf16(a, b2, acc2, 0, 0, 0);
    acc3 = __builtin_amdgcn_mfma_f32_16x16x32_bf16(a, b3, acc3, 0, 0, 0);
  }

  // row stats: lanes {q*16+c | q=0..3} jointly saw all 1024 elems of row c
  sum += __shfl_xor(sum, 16); sum += __shfl_xor(sum, 32);
  ssq += __shfl_xor(ssq, 16); ssq += __shfl_xor(ssq, 32);
  const float mu  = sum * (1.0f / HDIM);
  const float var = ssq * (1.0f / HDIM) - mu * mu;
  const float rs  = rsqrtf(var + 1e-5f);

  const float sdw0 = g_wstat[  0 + c], sdw1 = g_wstat[ 16 + c],
              sdw2 = g_wstat[ 32 + c], sdw3 = g_wstat[ 48 + c];
  const float dbv0 = g_wstat[ 64 + c], dbv1 = g_wstat[ 80 + c],
              dbv2 = g_wstat[ 96 + c], dbv3 = g_wstat[112 + c];

  // correction + exact GELU + write g-tile (D row m = q*4+i; stats live in lane m)
#pragma unroll
  for (int i = 0; i < 4; ++i) {
    const int src  = q * 4 + i;
    const float m  = __shfl(mu, src);
    const float rv = __shfl(rs, src);
    float h0 = rv * (acc0[i] - m * sdw0) + dbv0;
    float h1 = rv * (acc1[i] - m * sdw1) + dbv1;
    float h2 = rv * (acc2[i] - m * sdw2) + dbv2;
    float h3 = rv * (acc3[i] - m * sdw3) + dbv3;
    short* grow = &gbf[w][src][c];
    grow[0]  = f2bf(0.5f * h0 * (1.0f + erff(h0 * 0.70710678118654752f)));
    grow[16] = f2bf(0.5f * h1 * (1.0f + erff(h1 * 0.70710678118654752f)));
    grow[32] = f2bf(0.5f * h2 * (1.0f + erff(h2 * 0.70710678118654752f)));
    grow[48] = f2bf(0.5f * h3 * (1.0f + erff(h3 * 0.70710678118654752f)));
  }

  // same-wave LDS write->read: compile-time ordering barrier; HW DS pipe is
  // in-order per wave and the compiler inserts the lgkmcnt wait for the reads.
  asm volatile("" ::: "memory");

  const s16x8 a0 = *(const s16x8*)&gbf[w][c][q * 8];       // k = 0..31
  const s16x8 a1 = *(const s16x8*)&gbf[w][c][32 + q * 8];  // k = 32..63

  const float* xr0 = x + (rowbase + q * 4 + 0) * HDIM + c;
  const float* xr1 = x + (rowbase + q * 4 + 1) * HDIM + c;
  const float* xr2 = x + (rowbase + q * 4 + 2) * HDIM + c;
  const float* xr3 = x + (rowbase + q * 4 + 3) * HDIM + c;
  float* or0 = out + (rowbase + q * 4 + 0) * HDIM + c;
  float* or1 = out + (rowbase + q * 4 + 1) * HDIM + c;
  float* or2 = out + (rowbase + q * 4 + 2) * HDIM + c;
  float* or3 = out + (rowbase + q * 4 + 3) * HDIM + c;
  const short* pu = uwb + (size_t)c * BDIM + q * 8;

#pragma unroll 4
  for (int nt = 0; nt < 64; ++nt) {
    const short* uwrow = pu + (size_t)nt * 16 * BDIM;
    s16x8 b0 = *(const s16x8*)(uwrow);
    s16x8 b1 = *(const s16x8*)(uwrow + 32);
    f32x4 o4 = {0.f,0.f,0.f,0.f};
    o4 = __builtin_amdgcn_mfma_f32_16x16x32_bf16(a0, b0, o4, 0, 0, 0);
    o4 = __builtin_amdgcn_mfma_f32_16x16x32_bf16(a1, b1, o4, 0, 0, 0);
    const float ubv = ub[nt * 16 + c];
    const int co = nt * 16;                            // imm-offset loads/stores
    or0[co] = o4[0] + ubv + xr0[co];                   // residual from fp32 x (L2-hot)
    or1[co] = o4[1] + ubv + xr1[co];
    or2[co] = o4[2] + ubv + xr2[co];
    or3[co] = o4[3] + ubv + xr3[co];
  }
}

extern "C" void kernel_launch(void* const* d_in, const int* in_sizes, int n_in,
                              void* d_out, int out_size, void* d_ws, size_t ws_size,
                              hipStream_t stream) {
  const float* x  = (const float*)d_in[0];
  const float* nw = (const float*)d_in[1];
  const float* nb = (const float*)d_in[2];
  const float* dw = (const float*)d_in[3];
  const float* db = (const float*)d_in[4];
  const float* uw = (const float*)d_in[5];
  const float* ub = (const float*)d_in[6];
  float* out = (float*)d_out;

  short* wsbf = (short*)d_ws;                         // exactly 256 KB bf16 weights
  prep_weights<<<65, 256, 0, stream>>>(dw, uw, nw, nb, db, wsbf);

  const int rows = in_sizes[0] / HDIM;                // 32768
  const int grid = rows / 64;                         // 512 blocks x 4 indep waves
  adapter_fused<<<grid, 256, 0, stream>>>(x, ub, wsbf, wsbf + 65536, out);
}